// Round 1
// baseline (52641.412 us; speedup 1.0000x reference)
//
#include <hip/hip_runtime.h>

#define NGWG 128          // gate workgroups
#define TSTEPS 8192

typedef unsigned int u32;
typedef unsigned long long u64;

__device__ __forceinline__ u32 rne16(float f) {
    u32 u = __float_as_uint(f);
    return (u + 0x7fffu + ((u >> 16) & 1u)) >> 16;
}
__device__ __forceinline__ u32 packbf(float a, float b) {
    return rne16(a) | (rne16(b) << 16);
}
__device__ __forceinline__ float bflo(u32 u) { return __uint_as_float(u << 16); }
__device__ __forceinline__ float bfhi(u32 u) { return __uint_as_float(u & 0xffff0000u); }

#if __has_builtin(__builtin_amdgcn_fdot2_f32_bf16)
typedef __bf16 bf16x2 __attribute__((ext_vector_type(2)));
__device__ __forceinline__ float dot2b(u32 w, u32 h, float acc) {
    return __builtin_amdgcn_fdot2_f32_bf16(__builtin_bit_cast(bf16x2, w),
                                           __builtin_bit_cast(bf16x2, h), acc, false);
}
#else
__device__ __forceinline__ float dot2b(u32 w, u32 h, float acc) {
    return acc + bflo(w) * bflo(h) + bfhi(w) * bfhi(h);
}
#endif

__device__ __forceinline__ float rsum64(float a) {
#pragma unroll
    for (int m = 1; m < 64; m <<= 1) a += __shfl_xor(a, m);
    return a;
}
__device__ __forceinline__ float sigm(float x) { return 1.f / (1.f + __expf(-x)); }

// ---------------- kernel 1: P[t][j] = W_if·fe_t + W_ia·pe_t + b_ih + b_hh ----------------
template <typename PT>
__global__ __launch_bounds__(256) void k_pre(const float* __restrict__ fe,
                                             const int* __restrict__ act,
                                             const float* __restrict__ aet,
                                             const float* __restrict__ wih,
                                             const float* __restrict__ bih,
                                             const float* __restrict__ bhh,
                                             PT* __restrict__ P) {
    __shared__ __align__(16) float xs[32][68];
    __shared__ int pa[32];
    const int b = blockIdx.x;
    const int t0 = (b >> 3) * 32;
    const int jb = b & 7;
    const int tid = threadIdx.x;
    const int j = jb * 256 + tid;
    float acc[32];
#pragma unroll
    for (int i = 0; i < 32; i++) acc[i] = 0.f;
    if (tid < 32) {
        int t = t0 + tid;
        pa[tid] = (t == 0) ? 12 : act[t - 1];
    }
    const float* wrow = wih + (size_t)j * 672;
    for (int c = 0; c < 8; c++) {
        __syncthreads();
        for (int i = tid; i < 32 * 68; i += 256) {
            int tl = i / 68, kk = i % 68;
            int kg = c * 68 + kk;
            float v = (kg < 512) ? fe[(size_t)(t0 + tl) * 512 + kg]
                                 : aet[pa[tl] * 32 + (kg - 512)];
            xs[tl][kk] = v;
        }
        __syncthreads();
#pragma unroll
        for (int m = 0; m < 17; m++) {
            int kg0 = c * 68 + 4 * m;
            int col = (kg0 < 512) ? kg0 : kg0 + 128;
            float4 w = *(const float4*)(wrow + col);
#pragma unroll
            for (int tl = 0; tl < 32; tl++) {
                float4 x = *(const float4*)(&xs[tl][4 * m]);
                acc[tl] += w.x * x.x + w.y * x.y + w.z * x.z + w.w * x.w;
            }
        }
    }
    float bias = bih[j] + bhh[j];
    int jq = j >> 9, jrem = j & 511, jg = jrem >> 2, ju = jrem & 3;
#pragma unroll 4
    for (int tl = 0; tl < 32; tl++) {
        size_t idx = ((size_t)(t0 + tl) * NGWG + jg) * 16 + 4 * jq + ju;
        float v = acc[tl] + bias;
        if constexpr (sizeof(PT) == 2) P[idx] = (PT)rne16(v);
        else P[idx] = v;
    }
}

// ---------------- kernel 2: keys0 / vals0 ----------------
__global__ __launch_bounds__(256) void k_kv(const float* __restrict__ mi,
                                            const float* __restrict__ wk,
                                            const float* __restrict__ bk,
                                            const float* __restrict__ wv,
                                            const float* __restrict__ bv,
                                            float* __restrict__ kv0) {
    int o = blockIdx.x * 256 + threadIdx.x;  // 0..32767
    int which = o >> 14;
    int rest = o & 16383;
    int s = rest >> 7, d = rest & 127;
    const float* W = which ? wv : wk;
    float acc = which ? bv[d] : bk[d];
    const float* mrow = mi + s * 128;
    const float* wrow = W + d * 128;
#pragma unroll
    for (int k = 0; k < 128; k += 4) {
        float4 a = *(const float4*)(mrow + k);
        float4 b2 = *(const float4*)(wrow + k);
        acc += a.x * b2.x + a.y * b2.y + a.z * b2.z + a.w * b2.w;
    }
    kv0[o] = acc;
}

// ---------------- kernel 3: sequential recurrence ----------------
template <typename PT>
__global__ __launch_bounds__(1024) void k_seq(const PT* __restrict__ P,
                                              const float* __restrict__ kv0,
                                              u64* __restrict__ hw,
                                              const float* __restrict__ Whh,
                                              const float* __restrict__ Wih,
                                              const float* __restrict__ Wq,
                                              const float* __restrict__ bq,
                                              const float* __restrict__ Ww,
                                              const float* __restrict__ bw,
                                              const float* __restrict__ wg,
                                              const float* __restrict__ bg,
                                              const float* __restrict__ Wcls,
                                              const float* __restrict__ bcls,
                                              float* __restrict__ out) {
    __shared__ __align__(16) float hfp[512];
    __shared__ __align__(16) u32 hbf[256];
    __shared__ __align__(16) float qwv[256];
    __shared__ float biasq[256];
    __shared__ float attn[128];
    __shared__ float warr[128];
    __shared__ float scr[128];
    __shared__ __align__(16) float part[1024];
    __shared__ float gats[16];
    __shared__ float retr[128];
    __shared__ float wgld[512];
    __shared__ float misc[4];

    const int tid = threadIdx.x;
    const int lane = tid & 63;
    const int wave = tid >> 6;
    const int g = blockIdx.x;

    if (g == NGWG) {
        // ---- logits workgroup ----
        float wc[8];
        float bc = 0.f;
        if (wave < 12) {
#pragma unroll
            for (int i = 0; i < 8; i++) wc[i] = Wcls[wave * 512 + 8 * lane + i];
            bc = bcls[wave];
        }
        for (int t = 0; t < TSTEPS; ++t) {
            if (tid < 512) {
                const u64* p = hw + ((size_t)((t + 1) & 3)) * 512 + tid;
                u64 v;
                do {
                    v = __hip_atomic_load(p, __ATOMIC_RELAXED, __HIP_MEMORY_SCOPE_AGENT);
                } while ((u32)(v >> 32) != (u32)(t + 1));
                hfp[tid] = __uint_as_float((u32)v);
            }
            __syncthreads();
            if (wave < 12) {
                float a = 0.f;
#pragma unroll
                for (int i = 0; i < 8; i++) a += wc[i] * hfp[8 * lane + i];
                a = rsum64(a);
                if (lane == 0) out[t * 12 + wave] = a + bc;
            }
            __syncthreads();
        }
        return;
    }

    // ---- gate workgroup ----
    const int seg = tid >> 8;   // 0..3 : 128-col segment for q/wv
    const int o = tid & 255;    // output (q: 0..127, wv: 128..255)
    const int s = tid >> 3;     // slot (keys, slot-major)
    const int dc = tid & 7;     // d-chunk for keys
    const int dv = tid >> 3;    // d for valsT
    const int s8 = tid & 7;     // slot group for valsT

    // persistent weights (registers)
    u32 whhp[4], wirp;
    {
        int r = wave;
        int row = ((r >> 2) << 9) + 4 * g + (r & 3);
        const float* wr = Whh + (size_t)row * 512 + 8 * lane;
        float4 a = *(const float4*)wr;
        float4 b2 = *(const float4*)(wr + 4);
        whhp[0] = packbf(a.x, a.y);
        whhp[1] = packbf(a.z, a.w);
        whhp[2] = packbf(b2.x, b2.y);
        whhp[3] = packbf(b2.z, b2.w);
        const float* ir = Wih + (size_t)row * 672 + 512 + 2 * lane;
        wirp = packbf(ir[0], ir[1]);
    }
    u32 wqw[64];
    {
        const float* src = ((o < 128) ? (Wq + (size_t)o * 512) : (Ww + (size_t)(o - 128) * 512)) + seg * 128;
#pragma unroll
        for (int i = 0; i < 32; i++) {
            float4 v = *(const float4*)(src + 4 * i);
            wqw[2 * i] = packbf(v.x, v.y);
            wqw[2 * i + 1] = packbf(v.z, v.w);
        }
    }
    float keys[16], valsT[16];
    {
        const float* kp = kv0 + s * 128 + 16 * dc;
#pragma unroll
        for (int i = 0; i < 16; i++) keys[i] = kp[i];
#pragma unroll
        for (int i = 0; i < 16; i++) valsT[i] = kv0[16384 + (16 * s8 + i) * 128 + dv];
    }
    float cst = 0.f;
    const float bg0 = bg[0];

    if (tid < 512) { hfp[tid] = 0.f; wgld[tid] = wg[tid]; }
    if (tid < 256) { hbf[tid] = 0u; biasq[tid] = (tid < 128) ? bq[tid] : bw[tid - 128]; }
    if (tid < 128) { attn[tid] = 0.f; warr[tid] = 0.f; }
    if (tid < 4) misc[tid] = 0.f;
    __syncthreads();

    const float SCALE = 0.08838834764831845f;  // 1/sqrt(128)

    for (int t = 0; t < TSTEPS; ++t) {
        // prefetch P early (depends only on t)
        float pv;
        {
            size_t pidx = ((size_t)t * NGWG + g) * 16 + wave;
            if constexpr (sizeof(PT) == 2) pv = __uint_as_float(((u32)P[pidx]) << 16);
            else pv = P[pidx];
        }
        // B: gather h_t (tagged words)
        if (t > 0) {
            if (tid < 512) {
                const u64* p = hw + ((size_t)(t & 3)) * 512 + tid;
                u64 v;
                do {
                    v = __hip_atomic_load(p, __ATOMIC_RELAXED, __HIP_MEMORY_SCOPE_AGENT);
                } while ((u32)(v >> 32) != (u32)t);
                float vf = __uint_as_float((u32)v);
                hfp[tid] = vf;
                float other = __shfl_xor(vf, 1);
                if ((tid & 1) == 0) hbf[tid >> 1] = packbf(vf, other);
            }
            __syncthreads();
        }
        // D: q/wv matvec (bf16 dot2) + wave15 computes gate_{t-1}
        {
            const uint4* hb = ((const uint4*)hbf) + (seg << 4);
            float a0 = 0.f, a1 = 0.f;
#pragma unroll
            for (int i = 0; i < 16; i += 2) {
                uint4 x = hb[i];
                uint4 y = hb[i + 1];
                a0 = dot2b(wqw[4 * i + 0], x.x, a0);
                a0 = dot2b(wqw[4 * i + 1], x.y, a0);
                a0 = dot2b(wqw[4 * i + 2], x.z, a0);
                a0 = dot2b(wqw[4 * i + 3], x.w, a0);
                a1 = dot2b(wqw[4 * i + 4], y.x, a1);
                a1 = dot2b(wqw[4 * i + 5], y.y, a1);
                a1 = dot2b(wqw[4 * i + 6], y.z, a1);
                a1 = dot2b(wqw[4 * i + 7], y.w, a1);
            }
            part[tid] = a0 + a1;
        }
        if (wave == 15) {
            float a = 0.f;
#pragma unroll
            for (int i = 0; i < 8; i++) a += wgld[8 * lane + i] * hfp[8 * lane + i];
            a = rsum64(a);
            if (lane == 0) misc[0] = sigm(a + bg0);
        }
        __syncthreads();
        if (tid < 256)
            qwv[tid] = part[tid] + part[tid + 256] + part[tid + 512] + part[tid + 768] + biasq[tid];
        __syncthreads();
        // E: raw scores on OLD keys
        {
            const float* qq = qwv + 16 * dc;
            float a = 0.f;
#pragma unroll
            for (int i = 0; i < 16; i++) a += keys[i] * qq[i];
            a += __shfl_xor(a, 1);
            a += __shfl_xor(a, 2);
            a += __shfl_xor(a, 4);
            if (dc == 0) scr[s] = a;
        }
        __syncthreads();
        // F: wave0 — lazy write-fixup, softmax, attn_adj, beta
        if (wave == 0) {
            float a = qwv[lane] * qwv[128 + lane] + qwv[64 + lane] * qwv[192 + lane];
            float wvq = rsum64(a);
            float wmask = (t >= 2) ? 1.f : 0.f;
            float mret = (t > 0) ? 1.f : 0.f;
            float gp = misc[0];
            float w0 = wmask * gp * attn[lane];
            float w1 = wmask * gp * attn[64 + lane];
            float s0 = (scr[lane] * (1.f - w0) + w0 * wvq) * SCALE;
            float s1 = (scr[64 + lane] * (1.f - w1) + w1 * wvq) * SCALE;
            float m = fmaxf(s0, s1);
#pragma unroll
            for (int k = 1; k < 64; k <<= 1) m = fmaxf(m, __shfl_xor(m, k));
            float e0 = __expf(s0 - m), e1 = __expf(s1 - m);
            float su = rsum64(e0 + e1);
            float inv = 1.f / su;
            float a0 = e0 * inv, a1 = e1 * inv;
            attn[lane] = a0;
            attn[64 + lane] = a1;
            warr[lane] = w0;
            warr[64 + lane] = w1;
            scr[lane] = a0 * (1.f - w0) * mret;
            scr[64 + lane] = a1 * (1.f - w1) * mret;
            float bp = rsum64(a0 * w0 + a1 * w1);
            if (lane == 0) misc[2] = bp * mret;
        }
        __syncthreads();
        // G: retrieved (valsT layout: 3 shuffles total)
        {
            float a = 0.f;
            const float* ap = scr + 16 * s8;
#pragma unroll
            for (int i = 0; i < 16; i++) a += ap[i] * valsT[i];
            a += __shfl_xor(a, 1);
            a += __shfl_xor(a, 2);
            a += __shfl_xor(a, 4);
            if (s8 == 0) retr[dv] = a + misc[2] * qwv[128 + dv];
        }
        __syncthreads();
        // H: gates slice
        {
            const float* hh = hfp + 8 * lane;
            float a = 0.f;
#pragma unroll
            for (int i = 0; i < 4; i++) {
                u32 u = whhp[i];
                a += bflo(u) * hh[2 * i] + bfhi(u) * hh[2 * i + 1];
            }
            const float* rr = retr + 2 * lane;
            a += bflo(wirp) * rr[0] + bfhi(wirp) * rr[1];
            a = rsum64(a);
            if (lane == 0) gats[wave] = a + pv;
        }
        __syncthreads();
        // I: LSTM elementwise + tagged h store
        if (tid < 4) {
            float gi = gats[tid], gf = gats[4 + tid], gg2 = gats[8 + tid], go = gats[12 + tid];
            cst = sigm(gf) * cst + sigm(gi) * tanhf(gg2);
            float hn = sigm(go) * tanhf(cst);
            u64 wv64 = ((u64)(u32)(t + 1) << 32) | (u64)__float_as_uint(hn);
            __hip_atomic_store(hw + ((size_t)((t + 1) & 3)) * 512 + 4 * g + tid, wv64,
                               __ATOMIC_RELAXED, __HIP_MEMORY_SCOPE_AGENT);
        }
        // J: materialize memory update (off critical path)
        if (t >= 2) {
            float w = warr[s];
            const float* wvp = qwv + 128 + 16 * dc;
#pragma unroll
            for (int i = 0; i < 16; i++) keys[i] += w * (wvp[i] - keys[i]);
            float wvd = qwv[128 + dv];
#pragma unroll
            for (int i = 0; i < 16; i++) {
                float wj = warr[16 * s8 + i];
                valsT[i] += wj * (wvd - valsT[i]);
            }
        }
    }
}

extern "C" void kernel_launch(void* const* d_in, const int* in_sizes, int n_in,
                              void* d_out, int out_size, void* d_ws, size_t ws_size,
                              hipStream_t stream) {
    const float* fe = (const float*)d_in[0];
    const int* act = (const int*)d_in[1];
    const float* aet = (const float*)d_in[2];
    const float* wih = (const float*)d_in[3];
    const float* whh = (const float*)d_in[4];
    const float* bih = (const float*)d_in[5];
    const float* bhh = (const float*)d_in[6];
    const float* wcls = (const float*)d_in[7];
    const float* bcls = (const float*)d_in[8];
    const float* mi = (const float*)d_in[9];
    const float* Wq = (const float*)d_in[10];
    const float* bq = (const float*)d_in[11];
    const float* Wk = (const float*)d_in[12];
    const float* bk = (const float*)d_in[13];
    const float* Wv = (const float*)d_in[14];
    const float* bv = (const float*)d_in[15];
    const float* Ww = (const float*)d_in[16];
    const float* bw = (const float*)d_in[17];
    const float* wg = (const float*)d_in[18];
    const float* bg = (const float*)d_in[19];
    float* out = (float*)d_out;

    char* ws = (char*)d_ws;
    const size_t pfB = (size_t)TSTEPS * 2048 * 4;
    const size_t needF = pfB + 131072 + 16384;

    if (ws_size >= needF) {
        float* P = (float*)ws;
        float* kv0 = (float*)(ws + pfB);
        u64* hw = (u64*)(ws + pfB + 131072);
        k_pre<float><<<2048, 256, 0, stream>>>(fe, act, aet, wih, bih, bhh, P);
        k_kv<<<128, 256, 0, stream>>>(mi, Wk, bk, Wv, bv, kv0);
        k_seq<float><<<NGWG + 1, 1024, 0, stream>>>(P, kv0, hw, whh, wih, Wq, bq, Ww, bw,
                                                    wg, bg, wcls, bcls, out);
    } else {
        const size_t phB = (size_t)TSTEPS * 2048 * 2;
        unsigned short* P = (unsigned short*)ws;
        float* kv0 = (float*)(ws + phB);
        u64* hw = (u64*)(ws + phB + 131072);
        k_pre<unsigned short><<<2048, 256, 0, stream>>>(fe, act, aet, wih, bih, bhh, P);
        k_kv<<<128, 256, 0, stream>>>(mi, Wk, bk, Wv, bv, kv0);
        k_seq<unsigned short><<<NGWG + 1, 1024, 0, stream>>>(P, kv0, hw, whh, wih, Wq, bq,
                                                             Ww, bw, wg, bg, wcls, bcls, out);
    }
}